// Round 2
// 288.206 us; speedup vs baseline: 1.0854x; 1.0854x over previous
//
#include <hip/hip_runtime.h>
#include <hip/hip_bf16.h>
#include <stdint.h>

#define NBATCH 65536
#define LSEQ   64

typedef __attribute__((ext_vector_type(8))) _Float16 half8;
typedef __attribute__((ext_vector_type(2))) __fp16  fp16x2; // builtin cvt_pkrtz return type
typedef __attribute__((ext_vector_type(4))) float f32x4;
typedef __attribute__((ext_vector_type(4), aligned(8))) float f32x4u; // 8B-aligned 16B store
typedef __attribute__((ext_vector_type(4))) int   i32x4;

// relu + pack two f32 -> one dword of two f16 (RTZ; h2 values O(1), err ~5e-4)
static __device__ __forceinline__ int relu_pk_f16(float x, float y){
    union { fp16x2 h; int i; } u;
    u.h = __builtin_amdgcn_cvt_pkrtz(fmaxf(x, 0.f), fmaxf(y, 0.f));
    return u.i;
}

// 1 wave = 16 samples. Layer1 folded into f16 LDS table + packed-f16 carry FMA
// (carry softmax sums to 1: in*W1c = W1c1 + carry0*(W1c0-W1c1)). Layers 2+3 on
// MFMA 16x16x32 f16, fp32 accumulate. Block = 4 waves = 64 samples.
// Outputs staged in regs for 8 steps, flushed as 320B/sample bursts (5 full
// cache lines) so L2 write-combines -> no partial-line write amplification.
__global__ __launch_bounds__(256, 4)
void mlp_mfma_kernel(const int* __restrict__ a, const int* __restrict__ b,
                     const float* __restrict__ Ea, const float* __restrict__ Eb,
                     const float* __restrict__ W1, const float* __restrict__ b1,
                     const float* __restrict__ W2, const float* __restrict__ b2,
                     const float* __restrict__ Wd, const float* __restrict__ bd,
                     const float* __restrict__ Wc, const float* __restrict__ bc,
                     float* __restrict__ out)
{
    // Pab rows: 72 halfs (144B) -> 16B-aligned b128 chunks, 8 bank-slots spread
    __shared__ __attribute__((aligned(16))) _Float16 Pab[100*72];
    __shared__ unsigned char pkL[64*64];      // [step][local sample] packed digit pair
    __shared__ int scr[4][16*17 + 16];        // per-wave h2 pair-rows (f16x2 dwords), stride 17

    const int tid = threadIdx.x;
    const int wv  = tid >> 6;
    const int l   = tid & 63;
    const int q   = l >> 4;        // lane quad: k-group for A/B frags, row-group for C
    const int n   = l & 15;        // sample (col) within wave / row within A

    const int sBase = blockIdx.x * 64;

    // ---- stage digits: coalesced int4 loads -> packed bytes [s][n] ----
    {
        const i32x4* ap = (const i32x4*)(a + (size_t)sBase * LSEQ);
        const i32x4* bp = (const i32x4*)(b + (size_t)sBase * LSEQ);
        #pragma unroll
        for (int k = 0; k < 4; k++){
            int v = tid + k*256;                 // int4 index within block's 64x64
            i32x4 av = ap[v], bv = bp[v];
            int ns = v >> 4, s0 = (v & 15) << 2;
            pkL[(s0+0)*64 + ns] = (unsigned char)(av[0]*10 + bv[0]);
            pkL[(s0+1)*64 + ns] = (unsigned char)(av[1]*10 + bv[1]);
            pkL[(s0+2)*64 + ns] = (unsigned char)(av[2]*10 + bv[2]);
            pkL[(s0+3)*64 + ns] = (unsigned char)(av[3]*10 + bv[3]);
        }
    }

    // ---- layer-1 table (f16): Pab[p][j] = b1[j] + W1[j][17] + Ea[p/10]·W1[j][0:8] + Eb[p%10]·W1[j][8:16]
    for (int e = tid; e < 6400; e += 256){
        int p = e >> 6, j = e & 63;
        int da = p / 10, db = p - da*10;
        float acc = b1[j] + W1[j*18 + 17];
        #pragma unroll
        for (int k2 = 0; k2 < 8; k2++){
            acc = fmaf(Ea[da*8 + k2], W1[j*18 + k2],     acc);
            acc = fmaf(Eb[db*8 + k2], W1[j*18 + 8 + k2], acc);
        }
        Pab[p*72 + j] = (_Float16)acc;
    }

    // ---- per-lane constants (registers, f16 frags) ----
    half8 dcr[2];                                // (W1 col16 - col17) at this lane's k slots
    #pragma unroll
    for (int kc = 0; kc < 2; kc++){
        union { half8 v; _Float16 e[8]; } ud;
        #pragma unroll
        for (int jj = 0; jj < 8; jj++){
            int j = kc*32 + q*8 + jj;
            ud.e[jj] = (_Float16)(W1[j*18 + 16] - W1[j*18 + 17]);
        }
        dcr[kc] = ud.v;
    }

    half8 w2f[2][2];                             // A[m = n][k = q*8+jj], m-tile mt, k-chunk kc
    #pragma unroll
    for (int mt = 0; mt < 2; mt++)
        #pragma unroll
        for (int kc = 0; kc < 2; kc++){
            union { half8 v; _Float16 e[8]; } uw;
            int m = mt*16 + n;
            #pragma unroll
            for (int jj = 0; jj < 8; jj++)
                uw.e[jj] = (_Float16)W2[m*64 + kc*32 + q*8 + jj];
            w2f[mt][kc] = uw.v;
        }

    half8 w3f;                                   // rows 0-9 = Wd, 10-11 = Wc, 12-15 = 0
    {
        union { half8 v; _Float16 e[8]; } u3;
        #pragma unroll
        for (int jj = 0; jj < 8; jj++){
            int k = q*8 + jj;
            float x = 0.f;
            if (n < 10)      x = Wd[n*32+k];
            else if (n < 12) x = Wc[(n-10)*32+k];
            u3.e[jj] = (_Float16)x;
        }
        w3f = u3.v;
    }

    f32x4 bias2a = { b2[q*4+0], b2[q*4+1], b2[q*4+2], b2[q*4+3] };
    f32x4 bias2b = { b2[16+q*4+0], b2[16+q*4+1], b2[16+q*4+2], b2[16+q*4+3] };
    f32x4 bias3;
    #pragma unroll
    for (int r = 0; r < 4; r++){
        int m = q*4 + r;
        bias3[r] = (m < 10) ? bd[m] : (m < 12 ? bc[m-10] : 0.f);
    }

    __syncthreads();

    const int tn = sBase + wv*16 + n;            // this lane's sample
    const int lc = wv*16 + n;                    // pkL column
    int* scrw = scr[wv];
    char* outc = (char*)out;
    const unsigned dbase = (unsigned)tn*2560u + (unsigned)q*16u;       // digit section, bytes
    const unsigned cbase = (unsigned)(NBATCH*(size_t)LSEQ*10*4) + (unsigned)tn*512u; // carry sect
    const int bpa = (32 + n) << 2;               // bpermute addr: lane holding carry logits

    float carry = 1.0f;
    int idxN;                                    // digit-pair idx for step s+1
    half8 PA[2][2];                              // double-buffered Pab rows [parity][kc]
    {
        int i0 = pkL[lc];
        const _Float16* r0 = &Pab[i0*72 + q*8];
        PA[0][0] = *(const half8*)r0;
        PA[0][1] = *(const half8*)(r0 + 32);
        idxN = pkL[64 + lc];
    }

    for (int so = 0; so < LSEQ; so += 8){
        f32x4 stg[8];                            // 8 steps of acc3 (static-indexed after unroll)
        #pragma unroll
        for (int u = 0; u < 8; u++){
            const int s = so + u;
            const int cur = u & 1, nxt = cur ^ 1;

            // h1 = relu(P + carry*Dc) fully in packed f16 (v_pk_fma/v_pk_max)
            _Float16 ch = (_Float16)carry;
            half8 c8 = {ch,ch,ch,ch,ch,ch,ch,ch};
            half8 z  = {};
            half8 h10 = __builtin_elementwise_max(PA[cur][0] + c8*dcr[0], z);
            half8 h11 = __builtin_elementwise_max(PA[cur][1] + c8*dcr[1], z);

            // prefetch next step's Pab rows + idx two steps ahead (data-independent)
            {
                const _Float16* rn = &Pab[idxN*72 + q*8];
                PA[nxt][0] = *(const half8*)rn;
                PA[nxt][1] = *(const half8*)(rn + 32);
            }
            int idxN2 = pkL[(((s+2)&63)<<6) + lc];

            // layer 2: h2[32 x 16] = W2 · H1  (bias in acc init)
            f32x4 acc2a = bias2a, acc2b = bias2b;
            acc2a = __builtin_amdgcn_mfma_f32_16x16x32_f16(w2f[0][0], h10, acc2a, 0,0,0);
            acc2a = __builtin_amdgcn_mfma_f32_16x16x32_f16(w2f[0][1], h11, acc2a, 0,0,0);
            acc2b = __builtin_amdgcn_mfma_f32_16x16x32_f16(w2f[1][0], h10, acc2b, 0,0,0);
            acc2b = __builtin_amdgcn_mfma_f32_16x16x32_f16(w2f[1][1], h11, acc2b, 0,0,0);

            // re-partition h2: relu+pack f16 pairs in-register, bounce dwords via LDS.
            // pair-row pr holds rows (2pr, 2pr+1); C rows q*4+r pair naturally.
            scrw[(2*q+0)*17 + n]   = relu_pk_f16(acc2a[0], acc2a[1]);
            scrw[(2*q+1)*17 + n]   = relu_pk_f16(acc2a[2], acc2a[3]);
            scrw[(8+2*q+0)*17 + n] = relu_pk_f16(acc2b[0], acc2b[1]);
            scrw[(8+2*q+1)*17 + n] = relu_pk_f16(acc2b[2], acc2b[3]);
            __builtin_amdgcn_wave_barrier();     // keep reads after writes (same-wave DS in-order)
            int d0 = scrw[(q*4+0)*17 + n];       // pair-rows q*4..q*4+3 = rows q*8..q*8+7
            int d1 = scrw[(q*4+1)*17 + n];
            int d2 = scrw[(q*4+2)*17 + n];
            int d3 = scrw[(q*4+3)*17 + n];
            __builtin_amdgcn_wave_barrier();     // keep next iter's writes after these reads
            union { i32x4 d; half8 v; } uh2;
            uh2.d = i32x4{d0, d1, d2, d3};

            // layer 3: logits[16 x 16] (rows 0-9 digit, 10-11 carry, 12-15 pad)
            f32x4 acc3 = bias3;
            acc3 = __builtin_amdgcn_mfma_f32_16x16x32_f16(w3f, uh2.v, acc3, 0,0,0);

            // carry0 = sigmoid(c0 - c1); c0,c1 live in lane 32+n regs 2,3
            float diff = acc3[2] - acc3[3];
            int dv = __builtin_amdgcn_ds_bpermute(bpa, __float_as_int(diff));
            carry = 1.0f / (1.0f + __expf(-__int_as_float(dv)));

            stg[u] = acc3;
            idxN = idxN2;
        }

        // ---- flush 8 steps: 320B/sample digit burst (5 full lines) + 64B carry ----
        const unsigned dbq = dbase + (unsigned)so*40u;
        const unsigned cbq = cbase + (unsigned)so*8u;
        if (q < 2){
            #pragma unroll
            for (int u = 0; u < 8; u++)
                *(f32x4u*)(outc + dbq + u*40) = stg[u];
        } else if (q == 2){
            #pragma unroll
            for (int u = 0; u < 8; u++){
                *(float2*)(outc + dbq + u*40) = float2{stg[u][0], stg[u][1]};
                *(float2*)(outc + cbq + u*8)  = float2{stg[u][2], stg[u][3]};
            }
        }
    }
}

extern "C" void kernel_launch(void* const* d_in, const int* in_sizes, int n_in,
                              void* d_out, int out_size, void* d_ws, size_t ws_size,
                              hipStream_t stream) {
    const int*   a  = (const int*)d_in[0];
    const int*   b  = (const int*)d_in[1];
    const float* Ea = (const float*)d_in[2];
    const float* Eb = (const float*)d_in[3];
    const float* W1 = (const float*)d_in[4];
    const float* b1 = (const float*)d_in[5];
    const float* W2 = (const float*)d_in[6];
    const float* b2 = (const float*)d_in[7];
    const float* Wd = (const float*)d_in[8];
    const float* bd = (const float*)d_in[9];
    const float* Wc = (const float*)d_in[10];
    const float* bc = (const float*)d_in[11];

    mlp_mfma_kernel<<<NBATCH / 64, 256, 0, stream>>>(a, b, Ea, Eb, W1, b1,
                                                     W2, b2, Wd, bd, Wc, bc,
                                                     (float*)d_out);
}

// Round 5
// 286.386 us; speedup vs baseline: 1.0923x; 1.0064x over previous
//
#include <hip/hip_runtime.h>
#include <hip/hip_bf16.h>
#include <stdint.h>

#define NBATCH 65536
#define LSEQ   64

typedef __attribute__((ext_vector_type(8))) _Float16 half8;
typedef __attribute__((ext_vector_type(2))) __fp16  fp16x2; // builtin cvt_pkrtz return type
typedef __attribute__((ext_vector_type(4))) float f32x4;
typedef __attribute__((ext_vector_type(4), aligned(8))) float f32x4u; // 8B-aligned 16B store
typedef __attribute__((ext_vector_type(4))) int   i32x4;

// relu + pack two f32 -> one dword of two f16 (RTZ)
static __device__ __forceinline__ int relu_pk_f16(float x, float y){
    union { fp16x2 h; int i; } u;
    u.h = __builtin_amdgcn_cvt_pkrtz(fmaxf(x, 0.f), fmaxf(y, 0.f));
    return u.i;
}

// 1 wave = 16 samples. Layer1 folded into f16 LDS table + packed-f16 carry FMA
// (carry softmax sums to 1: in*W1c = W1c1 + carry0*(W1c0-W1c1)). Layers 2+3 on
// MFMA 16x16x32 f16, fp32 accumulate. Block = 4 waves = 64 samples.
//
// W2 rows are PERMUTED so that MFMA2's C-layout (lane(q,n): rows q*4+r and
// 16+q*4+r) directly yields the layer-3 B-fragment rows 8q..8q+7 — the h2
// re-partition LDS bounce is eliminated entirely (pure-register relu+pack).
// pkT is stored [sample][step] (stride 72) so step indices load as one
// ds_read_b64 per 8 steps (4-lane broadcast) + register byte extracts.
// Outputs staged in regs for 8 steps, flushed as 320B/sample bursts (5 full
// cache lines) so L2 write-combines.
__global__ __launch_bounds__(256, 4)
void mlp_mfma_kernel(const int* __restrict__ a, const int* __restrict__ b,
                     const float* __restrict__ Ea, const float* __restrict__ Eb,
                     const float* __restrict__ W1, const float* __restrict__ b1,
                     const float* __restrict__ W2, const float* __restrict__ b2,
                     const float* __restrict__ Wd, const float* __restrict__ bd,
                     const float* __restrict__ Wc, const float* __restrict__ bc,
                     float* __restrict__ out)
{
    // Pab rows: 72 halfs (144B): b128-aligned; random-row gather spreads
    // bank-quads as (idx+q) mod 8 -> near-uniform.
    __shared__ __attribute__((aligned(16))) _Float16 Pab[100*72];
    __shared__ __attribute__((aligned(8))) unsigned char pkT[64*72]; // [sample][step], 72B stride

    const int tid = threadIdx.x;
    const int wv  = tid >> 6;
    const int l   = tid & 63;
    const int q   = l >> 4;        // lane quad: k-group for A/B frags, row-group for C
    const int n   = l & 15;        // sample (col) within wave / row within A

    const int sBase = blockIdx.x * 64;

    // ---- stage digits: coalesced int4 loads -> packed dwords pkT[sample][step] ----
    {
        const i32x4* ap = (const i32x4*)(a + (size_t)sBase * LSEQ);
        const i32x4* bp = (const i32x4*)(b + (size_t)sBase * LSEQ);
        #pragma unroll
        for (int k = 0; k < 4; k++){
            int v = tid + k*256;                 // int4 index within block's 64x64
            i32x4 av = ap[v], bv = bp[v];
            int ns = v >> 4, s0 = (v & 15) << 2;
            unsigned pk = (unsigned)(av[0]*10 + bv[0])
                        | ((unsigned)(av[1]*10 + bv[1]) << 8)
                        | ((unsigned)(av[2]*10 + bv[2]) << 16)
                        | ((unsigned)(av[3]*10 + bv[3]) << 24);
            *(unsigned*)&pkT[ns*72 + s0] = pk;
        }
    }

    // ---- layer-1 table (f16): Pab[p][j] = b1[j] + W1[j][17] + Ea[p/10]·W1[j][0:8] + Eb[p%10]·W1[j][8:16]
    for (int e = tid; e < 6400; e += 256){
        int p = e >> 6, j = e & 63;
        int da = p / 10, db = p - da*10;
        float acc = b1[j] + W1[j*18 + 17];
        #pragma unroll
        for (int k2 = 0; k2 < 8; k2++){
            acc = fmaf(Ea[da*8 + k2], W1[j*18 + k2],     acc);
            acc = fmaf(Eb[db*8 + k2], W1[j*18 + 8 + k2], acc);
        }
        Pab[p*72 + j] = (_Float16)acc;
    }

    // ---- per-lane constants (registers, f16 frags) ----
    half8 dcr[2];                                // (W1 col16 - col17) at this lane's k slots
    #pragma unroll
    for (int kc = 0; kc < 2; kc++){
        union { half8 v; _Float16 e[8]; } ud;
        #pragma unroll
        for (int jj = 0; jj < 8; jj++){
            int j = kc*32 + q*8 + jj;
            ud.e[jj] = (_Float16)(W1[j*18 + 16] - W1[j*18 + 17]);
        }
        dcr[kc] = ud.v;
    }

    // W2 A-frags with PERMUTED rows: tile mt, lane row n loads
    // W2[8*(n>>2) + mt*4 + (n&3)] so C-slots give h2 rows 8q..8q+7 in-lane.
    half8 w2f[2][2];
    #pragma unroll
    for (int mt = 0; mt < 2; mt++){
        const int row = ((n >> 2) << 3) + (mt << 2) + (n & 3);
        #pragma unroll
        for (int kc = 0; kc < 2; kc++){
            union { half8 v; _Float16 e[8]; } uw;
            #pragma unroll
            for (int jj = 0; jj < 8; jj++)
                uw.e[jj] = (_Float16)W2[row*64 + kc*32 + q*8 + jj];
            w2f[mt][kc] = uw.v;
        }
    }

    half8 w3f;                                   // rows 0-9 = Wd, 10-11 = Wc, 12-15 = 0
    {
        union { half8 v; _Float16 e[8]; } u3;
        #pragma unroll
        for (int jj = 0; jj < 8; jj++){
            int k = q*8 + jj;
            float x = 0.f;
            if (n < 10)      x = Wd[n*32+k];
            else if (n < 12) x = Wc[(n-10)*32+k];
            u3.e[jj] = (_Float16)x;
        }
        w3f = u3.v;
    }

    // permuted biases: bias2a[r] = b2[8q+r], bias2b[r] = b2[8q+4+r]
    f32x4 bias2a = { b2[8*q+0], b2[8*q+1], b2[8*q+2], b2[8*q+3] };
    f32x4 bias2b = { b2[8*q+4], b2[8*q+5], b2[8*q+6], b2[8*q+7] };
    f32x4 bias3;
    #pragma unroll
    for (int r = 0; r < 4; r++){
        int m = q*4 + r;
        bias3[r] = (m < 10) ? bd[m] : (m < 12 ? bc[m-10] : 0.f);
    }

    __syncthreads();

    const int tn = sBase + wv*16 + n;            // this lane's sample
    const int lc = wv*16 + n;                    // pkT row
    char* outc = (char*)out;
    const unsigned dbase = (unsigned)tn*2560u + (unsigned)q*16u;       // digit section, bytes
    const unsigned cbase = (unsigned)(NBATCH*(size_t)LSEQ*10*4) + (unsigned)tn*512u; // carry sect
    const int bpa = (32 + n) << 2;               // bpermute addr: lane holding carry logits

    float carry = 1.0f;
    int c0, c1;                                  // current 8-step idx bytes
    half8 PA[2][2];                              // double-buffered Pab rows [parity][kc]
    {
        int2 cc = *(const int2*)&pkT[lc*72];
        c0 = cc.x; c1 = cc.y;
        int i0 = c0 & 255;
        const _Float16* r0 = &Pab[i0*72 + q*8];
        PA[0][0] = *(const half8*)r0;
        PA[0][1] = *(const half8*)(r0 + 32);
    }

    for (int so = 0; so < LSEQ; so += 8){
        // next block's idx bytes (last block: re-read own block; value unused)
        int2 nd = *(const int2*)&pkT[lc*72 + (so < 56 ? so + 8 : so)];

        f32x4 stg[8];                            // 8 steps of acc3 (static-indexed after unroll)
        #pragma unroll
        for (int u = 0; u < 8; u++){
            const int cur = u & 1, nxt = cur ^ 1;

            // h1 = relu(P + carry*Dc) fully in packed f16 (v_pk_fma/v_pk_max)
            _Float16 ch = (_Float16)carry;
            half8 c8 = {ch,ch,ch,ch,ch,ch,ch,ch};
            half8 z  = {};
            half8 h10 = __builtin_elementwise_max(PA[cur][0] + c8*dcr[0], z);
            half8 h11 = __builtin_elementwise_max(PA[cur][1] + c8*dcr[1], z);

            // prefetch next step's Pab rows (idx from registers, data-independent)
            // next-step byte for u=0..7: c0 bytes 1..3, c1 bytes 0..3, nd.x byte 0
            {
                int ib;
                if (u < 3)       ib = (c0 >> (8*(u+1))) & 255;
                else if (u < 7)  ib = (c1 >> (8*(u-3))) & 255;
                else             ib = nd.x & 255;
                const _Float16* rn = &Pab[ib*72 + q*8];
                PA[nxt][0] = *(const half8*)rn;
                PA[nxt][1] = *(const half8*)(rn + 32);
            }

            // layer 2: h2[32 x 16] = W2' · H1  (bias in acc init, rows permuted)
            f32x4 acc2a = bias2a, acc2b = bias2b;
            acc2a = __builtin_amdgcn_mfma_f32_16x16x32_f16(w2f[0][0], h10, acc2a, 0,0,0);
            acc2a = __builtin_amdgcn_mfma_f32_16x16x32_f16(w2f[0][1], h11, acc2a, 0,0,0);
            acc2b = __builtin_amdgcn_mfma_f32_16x16x32_f16(w2f[1][0], h10, acc2b, 0,0,0);
            acc2b = __builtin_amdgcn_mfma_f32_16x16x32_f16(w2f[1][1], h11, acc2b, 0,0,0);

            // lane(q,n) now holds h2 rows 8q..8q+7: build layer-3 B-frag in-register
            union { i32x4 d; half8 v; } uh2;
            uh2.d = i32x4{ relu_pk_f16(acc2a[0], acc2a[1]),
                           relu_pk_f16(acc2a[2], acc2a[3]),
                           relu_pk_f16(acc2b[0], acc2b[1]),
                           relu_pk_f16(acc2b[2], acc2b[3]) };

            // layer 3: logits[16 x 16] (rows 0-9 digit, 10-11 carry, 12-15 pad)
            f32x4 acc3 = bias3;
            acc3 = __builtin_amdgcn_mfma_f32_16x16x32_f16(w3f, uh2.v, acc3, 0,0,0);

            // carry0 = sigmoid(c0 - c1); carry logits live in lane 32+n regs 2,3
            float diff = acc3[2] - acc3[3];
            int dv = __builtin_amdgcn_ds_bpermute(bpa, __float_as_int(diff));
            carry = 1.0f / (1.0f + __expf(-__int_as_float(dv)));

            stg[u] = acc3;
        }

        // ---- flush 8 steps: 320B/sample digit burst (5 full lines) + 64B carry ----
        const unsigned dbq = dbase + (unsigned)so*40u;
        const unsigned cbq = cbase + (unsigned)so*8u;
        if (q < 2){
            #pragma unroll
            for (int u = 0; u < 8; u++)
                *(f32x4u*)(outc + dbq + u*40) = stg[u];
        } else if (q == 2){
            #pragma unroll
            for (int u = 0; u < 8; u++){
                *(float2*)(outc + dbq + u*40) = float2{stg[u][0], stg[u][1]};
                *(float2*)(outc + cbq + u*8)  = float2{stg[u][2], stg[u][3]};
            }
        }
        c0 = nd.x; c1 = nd.y;
    }
}

extern "C" void kernel_launch(void* const* d_in, const int* in_sizes, int n_in,
                              void* d_out, int out_size, void* d_ws, size_t ws_size,
                              hipStream_t stream) {
    const int*   a  = (const int*)d_in[0];
    const int*   b  = (const int*)d_in[1];
    const float* Ea = (const float*)d_in[2];
    const float* Eb = (const float*)d_in[3];
    const float* W1 = (const float*)d_in[4];
    const float* b1 = (const float*)d_in[5];
    const float* W2 = (const float*)d_in[6];
    const float* b2 = (const float*)d_in[7];
    const float* Wd = (const float*)d_in[8];
    const float* bd = (const float*)d_in[9];
    const float* Wc = (const float*)d_in[10];
    const float* bc = (const float*)d_in[11];

    mlp_mfma_kernel<<<NBATCH / 64, 256, 0, stream>>>(a, b, Ea, Eb, W1, b1,
                                                     W2, b2, Wd, bd, Wc, bc,
                                                     (float*)d_out);
}

// Round 8
// 277.701 us; speedup vs baseline: 1.1265x; 1.0313x over previous
//
#include <hip/hip_runtime.h>
#include <hip/hip_bf16.h>
#include <stdint.h>

#define NBATCH 65536
#define LSEQ   64

typedef __attribute__((ext_vector_type(8))) _Float16 half8;
typedef __attribute__((ext_vector_type(2))) __fp16  fp16x2; // builtin cvt_pkrtz return type
typedef __attribute__((ext_vector_type(4))) float f32x4;
typedef __attribute__((ext_vector_type(4), aligned(8))) float f32x4u; // 8B-aligned 16B store
typedef __attribute__((ext_vector_type(4))) int   i32x4;

// relu + pack two f32 -> one dword of two f16 (RTZ)
static __device__ __forceinline__ int relu_pk_f16(float x, float y){
    union { fp16x2 h; int i; } u;
    u.h = __builtin_amdgcn_cvt_pkrtz(fmaxf(x, 0.f), fmaxf(y, 0.f));
    return u.i;
}

// 1 wave = 16 samples. Layer1 folded into f16 LDS table + packed-f16 carry FMA.
// Layers 2+3 on MFMA 16x16x32 f16, fp32 accumulate. Block = 4 waves.
// W2 rows PERMUTED so MFMA2's C-layout directly yields the layer-3 B-frag
// (no LDS bounce). pkT [sample][step] -> one ds_read_b64 per 8 steps.
// All loop state in NAMED SCALARS (no scratch-demotable arrays).

struct StepCtx {
    half8 dcr0, dcr1, w2f00, w2f01, w2f10, w2f11, w3f;
    f32x4 bias2a, bias2b, bias3;
    const _Float16* Pab;
    int q, bpa;
};

// One step: h1 from pc0/pc1, prefetch row for byte ib into pn0/pn1, MFMA x5, carry.
static __device__ __forceinline__ f32x4 step_fn(const StepCtx& C, float& carry,
                                                const half8& pc0, const half8& pc1,
                                                half8& pn0, half8& pn1, int ib)
{
    _Float16 ch = (_Float16)carry;
    half8 c8 = {ch,ch,ch,ch,ch,ch,ch,ch};
    half8 z  = {};
    half8 h10 = __builtin_elementwise_max(pc0 + c8*C.dcr0, z);
    half8 h11 = __builtin_elementwise_max(pc1 + c8*C.dcr1, z);

    const _Float16* rn = C.Pab + (ib & 255)*72 + C.q*8;
    pn0 = *(const half8*)rn;
    pn1 = *(const half8*)(rn + 32);

    f32x4 acc2a = C.bias2a, acc2b = C.bias2b;
    acc2a = __builtin_amdgcn_mfma_f32_16x16x32_f16(C.w2f00, h10, acc2a, 0,0,0);
    acc2a = __builtin_amdgcn_mfma_f32_16x16x32_f16(C.w2f01, h11, acc2a, 0,0,0);
    acc2b = __builtin_amdgcn_mfma_f32_16x16x32_f16(C.w2f10, h10, acc2b, 0,0,0);
    acc2b = __builtin_amdgcn_mfma_f32_16x16x32_f16(C.w2f11, h11, acc2b, 0,0,0);

    union { i32x4 d; half8 v; } uh2;
    uh2.d = i32x4{ relu_pk_f16(acc2a[0], acc2a[1]), relu_pk_f16(acc2a[2], acc2a[3]),
                   relu_pk_f16(acc2b[0], acc2b[1]), relu_pk_f16(acc2b[2], acc2b[3]) };

    f32x4 acc3 = C.bias3;
    acc3 = __builtin_amdgcn_mfma_f32_16x16x32_f16(C.w3f, uh2.v, acc3, 0,0,0);

    float diff = acc3[2] - acc3[3];
    int dv = __builtin_amdgcn_ds_bpermute(C.bpa, __float_as_int(diff));
    carry = 1.0f / (1.0f + __expf(-__int_as_float(dv)));
    return acc3;
}

// Flush 4 staged steps: 160B/sample digit burst + 32B carry (L2 write-combines).
static __device__ __forceinline__ void flush4(char* outc, int q,
                                              unsigned dbq, unsigned cbq,
                                              const f32x4& g0, const f32x4& g1,
                                              const f32x4& g2, const f32x4& g3)
{
    if (q < 2){
        *(f32x4u*)(outc + dbq +   0) = g0;
        *(f32x4u*)(outc + dbq +  40) = g1;
        *(f32x4u*)(outc + dbq +  80) = g2;
        *(f32x4u*)(outc + dbq + 120) = g3;
    } else if (q == 2){
        *(float2*)(outc + dbq +   0) = float2{g0[0], g0[1]};
        *(float2*)(outc + dbq +  40) = float2{g1[0], g1[1]};
        *(float2*)(outc + dbq +  80) = float2{g2[0], g2[1]};
        *(float2*)(outc + dbq + 120) = float2{g3[0], g3[1]};
        *(float2*)(outc + cbq +   0) = float2{g0[2], g0[3]};
        *(float2*)(outc + cbq +   8) = float2{g1[2], g1[3]};
        *(float2*)(outc + cbq +  16) = float2{g2[2], g2[3]};
        *(float2*)(outc + cbq +  24) = float2{g3[2], g3[3]};
    }
}

__global__ __launch_bounds__(256, 4)
void mlp_mfma_kernel(const int* __restrict__ a, const int* __restrict__ b,
                     const float* __restrict__ Ea, const float* __restrict__ Eb,
                     const float* __restrict__ W1, const float* __restrict__ b1,
                     const float* __restrict__ W2, const float* __restrict__ b2,
                     const float* __restrict__ Wd, const float* __restrict__ bd,
                     const float* __restrict__ Wc, const float* __restrict__ bc,
                     float* __restrict__ out)
{
    __shared__ __attribute__((aligned(16))) _Float16 Pab[100*72];
    __shared__ __attribute__((aligned(8))) unsigned char pkT[64*72]; // [sample][step]

    const int tid = threadIdx.x;
    const int wv  = tid >> 6;
    const int l   = tid & 63;
    const int q   = l >> 4;        // lane quad: k-group for A/B frags, row-group for C
    const int n   = l & 15;        // sample (col) within wave / row within A

    const int sBase = blockIdx.x * 64;

    // ---- stage digits: coalesced int4 loads -> packed dwords pkT[sample][step] ----
    {
        const i32x4* ap = (const i32x4*)(a + (size_t)sBase * LSEQ);
        const i32x4* bp = (const i32x4*)(b + (size_t)sBase * LSEQ);
        #pragma unroll
        for (int k = 0; k < 4; k++){
            int v = tid + k*256;
            i32x4 av = ap[v], bv = bp[v];
            int ns = v >> 4, s0 = (v & 15) << 2;
            unsigned pk = (unsigned)(av[0]*10 + bv[0])
                        | ((unsigned)(av[1]*10 + bv[1]) << 8)
                        | ((unsigned)(av[2]*10 + bv[2]) << 16)
                        | ((unsigned)(av[3]*10 + bv[3]) << 24);
            *(unsigned*)&pkT[ns*72 + s0] = pk;
        }
    }

    // ---- layer-1 table (f16): Pab[p][j] = b1[j] + W1[j][17] + Ea[p/10]·W1[j][0:8] + Eb[p%10]·W1[j][8:16]
    for (int e = tid; e < 6400; e += 256){
        int p = e >> 6, j = e & 63;
        int da = p / 10, db = p - da*10;
        float acc = b1[j] + W1[j*18 + 17];
        #pragma unroll
        for (int k2 = 0; k2 < 8; k2++){
            acc = fmaf(Ea[da*8 + k2], W1[j*18 + k2],     acc);
            acc = fmaf(Eb[db*8 + k2], W1[j*18 + 8 + k2], acc);
        }
        Pab[p*72 + j] = (_Float16)acc;
    }

    // ---- per-lane constants (named f16 frags) ----
    StepCtx C;
    C.Pab = Pab; C.q = q; C.bpa = (32 + n) << 2;
    {
        union { half8 v; _Float16 e[8]; } ud;
        #pragma unroll
        for (int jj = 0; jj < 8; jj++) ud.e[jj] = (_Float16)(W1[(q*8+jj)*18 + 16] - W1[(q*8+jj)*18 + 17]);
        C.dcr0 = ud.v;
        #pragma unroll
        for (int jj = 0; jj < 8; jj++) ud.e[jj] = (_Float16)(W1[(32+q*8+jj)*18 + 16] - W1[(32+q*8+jj)*18 + 17]);
        C.dcr1 = ud.v;
    }

    // W2 A-frags with PERMUTED rows: lane row n covers W2 rows 8*(n>>2)+(n&3)
    // (+4 for tile b) so C-slots give h2 rows 8q..8q+7 in-lane.
    {
        union { half8 v; _Float16 e[8]; } uw;
        const int r0 = ((n >> 2) << 3) + (n & 3);      // tile a
        const int r1 = r0 + 4;                         // tile b
        #pragma unroll
        for (int jj = 0; jj < 8; jj++) uw.e[jj] = (_Float16)W2[r0*64 +      q*8 + jj];
        C.w2f00 = uw.v;
        #pragma unroll
        for (int jj = 0; jj < 8; jj++) uw.e[jj] = (_Float16)W2[r0*64 + 32 + q*8 + jj];
        C.w2f01 = uw.v;
        #pragma unroll
        for (int jj = 0; jj < 8; jj++) uw.e[jj] = (_Float16)W2[r1*64 +      q*8 + jj];
        C.w2f10 = uw.v;
        #pragma unroll
        for (int jj = 0; jj < 8; jj++) uw.e[jj] = (_Float16)W2[r1*64 + 32 + q*8 + jj];
        C.w2f11 = uw.v;
    }

    // W3 A-frag: rows 0-9 = Wd, 10-11 = Wc, 12-15 = 0
    {
        union { half8 v; _Float16 e[8]; } u3;
        #pragma unroll
        for (int jj = 0; jj < 8; jj++){
            int k = q*8 + jj;
            float x = 0.f;
            if (n < 10)      x = Wd[n*32+k];
            else if (n < 12) x = Wc[(n-10)*32+k];
            u3.e[jj] = (_Float16)x;
        }
        C.w3f = u3.v;
    }

    // permuted biases: bias2a[r] = b2[8q+r], bias2b[r] = b2[8q+4+r]
    C.bias2a = f32x4{ b2[8*q+0], b2[8*q+1], b2[8*q+2], b2[8*q+3] };
    C.bias2b = f32x4{ b2[8*q+4], b2[8*q+5], b2[8*q+6], b2[8*q+7] };
    {
        float t0 = (q*4+0 < 10) ? bd[q*4+0] : ((q*4+0 < 12) ? bc[q*4+0-10] : 0.f);
        float t1 = (q*4+1 < 10) ? bd[q*4+1] : ((q*4+1 < 12) ? bc[q*4+1-10] : 0.f);
        float t2 = (q*4+2 < 10) ? bd[q*4+2] : ((q*4+2 < 12) ? bc[q*4+2-10] : 0.f);
        float t3 = (q*4+3 < 10) ? bd[q*4+3] : ((q*4+3 < 12) ? bc[q*4+3-10] : 0.f);
        C.bias3 = f32x4{t0, t1, t2, t3};
    }

    __syncthreads();

    const int tn = sBase + wv*16 + n;            // this lane's sample
    const int lc = wv*16 + n;                    // pkT row
    char* outc = (char*)out;
    const unsigned dbase = (unsigned)tn*2560u + (unsigned)q*16u;       // digit section, bytes
    const unsigned cbase = (unsigned)(NBATCH*(size_t)LSEQ*10*4) + (unsigned)tn*512u; // carry sect

    float carry = 1.0f;
    int c0, c1;                                  // current 8-step idx bytes
    half8 PAa0, PAa1, PAb0, PAb1;                // named ping-pong Pab rows
    {
        int2 cc = *(const int2*)&pkT[lc*72];
        c0 = cc.x; c1 = cc.y;
        const _Float16* r0 = &Pab[(c0 & 255)*72 + q*8];
        PAa0 = *(const half8*)r0;
        PAa1 = *(const half8*)(r0 + 32);
    }

    for (int so = 0; so < LSEQ; so += 8){
        // next block's idx bytes (last block: re-read own block; value unused)
        int2 nd = *(const int2*)&pkT[lc*72 + (so < 56 ? so + 8 : so)];

        f32x4 g0, g1, g2, g3;
        // steps so+0 .. so+3 (prefetch bytes 1..4 of this block)
        g0 = step_fn(C, carry, PAa0, PAa1, PAb0, PAb1, c0 >> 8);
        g1 = step_fn(C, carry, PAb0, PAb1, PAa0, PAa1, c0 >> 16);
        g2 = step_fn(C, carry, PAa0, PAa1, PAb0, PAb1, c0 >> 24);
        g3 = step_fn(C, carry, PAb0, PAb1, PAa0, PAa1, c1);
        flush4(outc, q, dbase + (unsigned)so*40u, cbase + (unsigned)so*8u, g0, g1, g2, g3);
        // steps so+4 .. so+7 (prefetch bytes 5..7, then next block's byte 0)
        g0 = step_fn(C, carry, PAa0, PAa1, PAb0, PAb1, c1 >> 8);
        g1 = step_fn(C, carry, PAb0, PAb1, PAa0, PAa1, c1 >> 16);
        g2 = step_fn(C, carry, PAa0, PAa1, PAb0, PAb1, c1 >> 24);
        g3 = step_fn(C, carry, PAb0, PAb1, PAa0, PAa1, nd.x);
        flush4(outc, q, dbase + (unsigned)(so+4)*40u, cbase + (unsigned)(so+4)*8u, g0, g1, g2, g3);

        c0 = nd.x; c1 = nd.y;
    }
}

extern "C" void kernel_launch(void* const* d_in, const int* in_sizes, int n_in,
                              void* d_out, int out_size, void* d_ws, size_t ws_size,
                              hipStream_t stream) {
    const int*   a  = (const int*)d_in[0];
    const int*   b  = (const int*)d_in[1];
    const float* Ea = (const float*)d_in[2];
    const float* Eb = (const float*)d_in[3];
    const float* W1 = (const float*)d_in[4];
    const float* b1 = (const float*)d_in[5];
    const float* W2 = (const float*)d_in[6];
    const float* b2 = (const float*)d_in[7];
    const float* Wd = (const float*)d_in[8];
    const float* bd = (const float*)d_in[9];
    const float* Wc = (const float*)d_in[10];
    const float* bc = (const float*)d_in[11];

    mlp_mfma_kernel<<<NBATCH / 64, 256, 0, stream>>>(a, b, Ea, Eb, W1, b1,
                                                     W2, b2, Wd, bd, Wc, bc,
                                                     (float*)d_out);
}